// Round 11
// baseline (328.712 us; speedup 1.0000x reference)
//
#include <hip/hip_runtime.h>
#include <hip/hip_bf16.h>

using bf16 = __hip_bfloat16;
typedef __attribute__((ext_vector_type(8))) short short8;
typedef __attribute__((ext_vector_type(4))) float float4v;

#define N_NODES 40962
#define N_EDGES 245760
#define NP      41024      // 641*64, gather-written node rows
#define NPAD    41088      // 321*128, buffer row capacity for 128-row GEMM blocks
#define KG      10
#define SCAN_B  256
#define NBLK    ((NP + SCAN_B - 1) / SCAN_B)   // 161
#define GRIDM   (NPAD / 128)                   // 321 gemm blocks (128 rows each)

// fused prep grid partition
#define CVT_V   (N_NODES * 64 / 8)             // 327696 vectors of 8
#define CVT_BLK ((CVT_V + 255) / 256)          // 1281
#define W3_BLK  (N_EDGES / 256)                // 960
#define PACK_N  (64 * 704 + 2 * 128 * 704)     // 225280
#define PACK_BLK (PACK_N / 256)                // 880

// k-dim ordering (shared by z stores, x/h frag layout, and B pack):
//   k in [0,512):   cin = k>>3,        kg = k&7      (k = cin*8+kg)
//   k in [512,640): cin = (k-512)>>1,  kg = 8+((k-512)&1)
//   k in [640,704): root row cin = k-640
// Frag layouts (no LDS GEMM; memory layout == MFMA fragment layout):
//   Zf[kc][node][32]  kc=0..19  : element t -> k = kc*32+t   (row stride NPAD)
//   Xf/hf[c][node][32] c=0..1   : element t -> cin = c*32+t  (row stride NPAD)
//   Bp[((n*22+kc)*64+lane)*8+j] : col = n*16+(lane&15), k = kc*32+(lane>>4)*8+j

// flag[0] == 1 -> float inputs/outputs are f32 ; 0 -> bf16
__device__ __forceinline__ float ldf(const void* p, size_t i, int isf32) {
    return isf32 ? ((const float*)p)[i] : __bfloat162float(((const bf16*)p)[i]);
}
__device__ __forceinline__ float blo(unsigned u) { return __uint_as_float(u << 16); }
__device__ __forceinline__ float bhi(unsigned u) { return __uint_as_float(u & 0xffff0000u); }
__device__ __forceinline__ unsigned pk2(float a, float b) {
    union { bf16 h[2]; unsigned u; } t;
    t.h[0] = __float2bfloat16(a);
    t.h[1] = __float2bfloat16(b);
    return t.u;
}
__device__ __forceinline__ int rfl(int v) { return __builtin_amdgcn_readfirstlane(v); }

// ---------------- fused dtype detector + degree count ----------------
__global__ void k_detect_count(const void* x, const int* __restrict__ ei,
                               int* __restrict__ flag, int* __restrict__ deg) {
    if (blockIdx.x == 0) {
        __shared__ int huge_c, zero_even;
        if (threadIdx.x == 0) { huge_c = 0; zero_even = 0; }
        __syncthreads();
        const bf16* xb = (const bf16*)x;
        int lh = 0, lz = 0;
        for (int i = threadIdx.x; i < 8192; i += 256) {
            float v = __bfloat162float(xb[i]);
            if (!(fabsf(v) <= 1e4f)) lh++;
            if ((i & 1) == 0 && v == 0.0f) lz++;
        }
        atomicAdd(&huge_c, lh);
        atomicAdd(&zero_even, lz);
        __syncthreads();
        if (threadIdx.x == 0) flag[0] = (huge_c > 0 || zero_even > 3000) ? 1 : 0;
    } else {
        int e = (blockIdx.x - 1) * 256 + threadIdx.x;
        if (e < N_EDGES) atomicAdd(&deg[ei[N_EDGES + e]], 1);
    }
}

// ---------------- scan stage 1: block-local exclusive + block sums ----------------
__global__ void k_scan1(const int* __restrict__ deg, int* __restrict__ offs,
                        int* __restrict__ bsum) {
    __shared__ int buf[SCAN_B];
    int t = threadIdx.x, b = blockIdx.x;
    int i = b * SCAN_B + t;
    int v = (i < NP) ? deg[i] : 0;
    buf[t] = v;
    __syncthreads();
    for (int off = 1; off < SCAN_B; off <<= 1) {
        int a = (t >= off) ? buf[t - off] : 0;
        __syncthreads();
        buf[t] += a;
        __syncthreads();
    }
    if (i < NP) offs[i] = buf[t] - v;
    if (t == SCAN_B - 1) bsum[b] = buf[t];
}

// ---------------- scan stage 2 (merged): each block re-scans bsum locally ----------------
__global__ void k_scan3m(int* __restrict__ offs, const int* __restrict__ bsum,
                         const int* __restrict__ deg, int* __restrict__ cur,
                         float* __restrict__ invdeg) {
    __shared__ int buf[256];
    int t = threadIdx.x, b = blockIdx.x;
    int v = (t < NBLK) ? bsum[t] : 0;
    buf[t] = v;
    __syncthreads();
    for (int off = 1; off < 256; off <<= 1) {
        int a = (t >= off) ? buf[t - off] : 0;
        __syncthreads();
        buf[t] += a;
        __syncthreads();
    }
    int bofs = (b > 0) ? buf[b - 1] : 0;
    int total = buf[NBLK - 1];
    int i = b * 256 + t;
    if (i < NP) {
        int o = offs[i] + bofs;
        offs[i] = o;
        cur[i] = o;
        int d = deg[i];
        invdeg[i] = 1.0f / (float)(d > 1 ? d : 1);
    }
    if (i == 0) offs[NP] = total;
}

// ---------------- CSR fill ----------------
__global__ void k_fill(const int* __restrict__ ei, int* __restrict__ cur,
                       int* __restrict__ csr) {
    int e = blockIdx.x * 256 + threadIdx.x;
    if (e < N_EDGES) {
        int pos = atomicAdd(&cur[ei[N_EDGES + e]], 1);
        csr[pos] = e;
    }
}

// ---------------- gaussian weights helper ----------------
__device__ __forceinline__ void gw_one(float p0, float p1, const void* mu,
                                       const void* sg, int f, float* out) {
#pragma unroll
    for (int k = 0; k < KG; k++) {
        float m0 = ldf(mu, 2 * k + 0, f), m1 = ldf(mu, 2 * k + 1, f);
        float s0 = ldf(sg, 2 * k + 0, f), s1 = ldf(sg, 2 * k + 1, f);
        float d0 = p0 - m0, d1 = p1 - m1;
        float t = -0.5f * (d0 * d0 / (1e-15f + s0 * s0) + d1 * d1 / (1e-15f + s1 * s1));
        out[k] = __expf(t);
    }
}

// ---------------- B pack in fragment order ----------------
__device__ __forceinline__ void pack_frag(const void* g, const void* root, int f,
                                          int idx, int Cout, bf16* Bp) {
    int j = idx & 7;
    int lane = (idx >> 3) & 63;
    int rem = idx >> 9;
    int kc = rem % 22;
    int n = rem / 22;
    int col = n * 16 + (lane & 15);
    int k = kc * 32 + (lane >> 4) * 8 + j;
    float v;
    if (k < 512) {
        int cin = k >> 3, kg = k & 7;
        v = ldf(g, (size_t)cin * (KG * Cout) + (size_t)kg * Cout + col, f);
    } else if (k < 640) {
        int jj = k - 512;
        int cin = jj >> 1, kg = 8 + (jj & 1);
        v = ldf(g, (size_t)cin * (KG * Cout) + (size_t)kg * Cout + col, f);
    } else {
        v = ldf(root, (size_t)(k - 640) * Cout + col, f);
    }
    Bp[idx] = __float2bfloat16(v);
}

// ---------------- fused prep: cvt x->Xf | w3 | pack3 ----------------
__global__ void k_prep_all(const void* __restrict__ x, const void* __restrict__ pseudo,
                           const void* mu1, const void* sg1, const void* mu2,
                           const void* sg2, const void* mus, const void* sgs,
                           const void* g1, const void* root1, const void* g2,
                           const void* root2, const void* gs, const void* roots,
                           const int* __restrict__ flag, bf16* __restrict__ Xf,
                           bf16* __restrict__ wab, bf16* __restrict__ w2b,
                           bf16* wt1p, bf16* wt2p, bf16* wtsp) {
    int b = blockIdx.x;
    int tid = threadIdx.x;
    int f = flag[0];
    if (b < CVT_BLK) {
        int i = b * 256 + tid;
        if (i < CVT_V) {
            int node = i >> 3, j = i & 7;   // covers x[node][j*8 .. j*8+8)
            uint4 u;
            if (f) {
                const float4* xf = (const float4*)x;
                float4 a = xf[2 * i], c = xf[2 * i + 1];
                union { bf16 t[8]; uint4 u; } tt;
                tt.t[0] = __float2bfloat16(a.x); tt.t[1] = __float2bfloat16(a.y);
                tt.t[2] = __float2bfloat16(a.z); tt.t[3] = __float2bfloat16(a.w);
                tt.t[4] = __float2bfloat16(c.x); tt.t[5] = __float2bfloat16(c.y);
                tt.t[6] = __float2bfloat16(c.z); tt.t[7] = __float2bfloat16(c.w);
                u = tt.u;
            } else {
                u = ((const uint4*)x)[i];
            }
            *(uint4*)(Xf + ((size_t)(j >> 2) * NPAD + node) * 32 + (j & 3) * 8) = u;
        }
    } else if (b < CVT_BLK + W3_BLK) {
        int e = (b - CVT_BLK) * 256 + tid;
        float p0 = ldf(pseudo, (size_t)e * 2 + 0, f);
        float p1 = ldf(pseudo, (size_t)e * 2 + 1, f);
        float o1[KG], o2[KG], os[KG];
        gw_one(p0, p1, mu1, sg1, f, o1);
        gw_one(p0, p1, mu2, sg2, f, o2);
        gw_one(p0, p1, mus, sgs, f, os);
        unsigned* d = (unsigned*)(wab + (size_t)e * 20);
        d[0] = pk2(o1[0], o1[1]); d[1] = pk2(o1[2], o1[3]);
        d[2] = pk2(o1[4], o1[5]); d[3] = pk2(o1[6], o1[7]);
        d[4] = pk2(o1[8], o1[9]);
        d[5] = pk2(os[0], os[1]); d[6] = pk2(os[2], os[3]);
        d[7] = pk2(os[4], os[5]); d[8] = pk2(os[6], os[7]);
        d[9] = pk2(os[8], os[9]);
        unsigned* d2 = (unsigned*)(w2b + (size_t)e * 10);
        d2[0] = pk2(o2[0], o2[1]); d2[1] = pk2(o2[2], o2[3]);
        d2[2] = pk2(o2[4], o2[5]); d2[3] = pk2(o2[6], o2[7]);
        d2[4] = pk2(o2[8], o2[9]);
    } else {
        int idx = (b - CVT_BLK - W3_BLK) * 256 + tid;
        if (idx < 64 * 704) {
            pack_frag(g1, root1, f, idx, 64, wt1p);
        } else if (idx < 64 * 704 + 128 * 704) {
            pack_frag(g2, root2, f, idx - 64 * 704, 128, wt2p);
        } else {
            pack_frag(gs, roots, f, idx - 64 * 704 - 128 * 704, 128, wtsp);
        }
    }
}

// ---------------- z store into frag layout Zf[kc][node][32] (stride NPAD) --------
__device__ __forceinline__ void store_zf(bf16* Zf, int wid, int lane, const float* a,
                                         float inv) {
    union { bf16 h[8]; uint4 u; } p;
#pragma unroll
    for (int k = 0; k < 8; k++) p.h[k] = __float2bfloat16(a[k] * inv);
    *(uint4*)(Zf + ((size_t)(lane >> 2) * NPAD + wid) * 32 + (lane & 3) * 8) = p.u;
    *(unsigned*)(Zf + ((size_t)(16 + (lane >> 4)) * NPAD + wid) * 32 + (lane & 15) * 2) =
        pk2(a[8] * inv, a[9] * inv);
}

// X frag-layout read: cin = lane -> chunk lane>>5, t = lane&31
__device__ __forceinline__ float ldx_frag(const bf16* X, int src, int lane) {
    return __bfloat162float(X[((size_t)(lane >> 5) * NPAD + src) * 32 + (lane & 31)]);
}

__device__ __forceinline__ int csr_at(const int* csr, int idx) {
    if (idx > N_EDGES - 1) idx = N_EDGES - 1;
    return rfl(csr[idx]);
}

// ---------------- dual gather, scalarized + software-pipelined ----------------
__global__ void k_gather2(const int* __restrict__ ei, const int* __restrict__ offs,
                          const int* __restrict__ csr, const bf16* __restrict__ wab,
                          const float* __restrict__ invdeg, const bf16* __restrict__ X,
                          bf16* __restrict__ Za, bf16* __restrict__ Zb) {
    int wid = (blockIdx.x * 256 + threadIdx.x) >> 6;
    int lane = threadIdx.x & 63;
    if (wid >= NP) return;
    float aa[KG], ab[KG];
#pragma unroll
    for (int k = 0; k < KG; k++) { aa[k] = 0.0f; ab[k] = 0.0f; }
    int beg = rfl(offs[wid]);
    int end = rfl(offs[wid + 1]);
    int cnt = end - beg;

    int e0 = csr_at(csr, beg + 0);
    int e1 = csr_at(csr, beg + 1);
    int e2 = csr_at(csr, beg + 2);
    int s1 = rfl(ei[e1]);
    const unsigned* wp0 = (const unsigned*)(wab + (size_t)e0 * 20);
    unsigned c0 = wp0[0], c1 = wp0[1], c2 = wp0[2], c3 = wp0[3], c4 = wp0[4];
    unsigned c5 = wp0[5], c6 = wp0[6], c7 = wp0[7], c8 = wp0[8], c9 = wp0[9];
    const unsigned* wp1 = (const unsigned*)(wab + (size_t)e1 * 20);
    unsigned n0 = wp1[0], n1 = wp1[1], n2 = wp1[2], n3 = wp1[3], n4 = wp1[4];
    unsigned n5 = wp1[5], n6 = wp1[6], n7 = wp1[7], n8 = wp1[8], n9 = wp1[9];
    int s0 = rfl(ei[e0]);
    float xv = ldx_frag(X, s0, lane);

    for (int t = 0; t < cnt; ++t) {
        int e3 = csr_at(csr, beg + t + 3);
        int s2 = rfl(ei[e2]);
        const unsigned* wp2 = (const unsigned*)(wab + (size_t)e2 * 20);
        unsigned m0 = wp2[0], m1 = wp2[1], m2 = wp2[2], m3 = wp2[3], m4 = wp2[4];
        unsigned m5 = wp2[5], m6 = wp2[6], m7 = wp2[7], m8 = wp2[8], m9 = wp2[9];
        float xv1 = ldx_frag(X, s1, lane);
        aa[0] += blo(c0) * xv; aa[1] += bhi(c0) * xv;
        aa[2] += blo(c1) * xv; aa[3] += bhi(c1) * xv;
        aa[4] += blo(c2) * xv; aa[5] += bhi(c2) * xv;
        aa[6] += blo(c3) * xv; aa[7] += bhi(c3) * xv;
        aa[8] += blo(c4) * xv; aa[9] += bhi(c4) * xv;
        ab[0] += blo(c5) * xv; ab[1] += bhi(c5) * xv;
        ab[2] += blo(c6) * xv; ab[3] += bhi(c6) * xv;
        ab[4] += blo(c7) * xv; ab[5] += bhi(c7) * xv;
        ab[6] += blo(c8) * xv; ab[7] += bhi(c8) * xv;
        ab[8] += blo(c9) * xv; ab[9] += bhi(c9) * xv;
        e2 = e3; s1 = s2; xv = xv1;
        c0 = n0; c1 = n1; c2 = n2; c3 = n3; c4 = n4;
        c5 = n5; c6 = n6; c7 = n7; c8 = n8; c9 = n9;
        n0 = m0; n1 = m1; n2 = m2; n3 = m3; n4 = m4;
        n5 = m5; n6 = m6; n7 = m7; n8 = m8; n9 = m9;
    }
    float inv = invdeg[wid];
    store_zf(Za, wid, lane, aa, inv);
    store_zf(Zb, wid, lane, ab, inv);
}

// ---------------- single gather, scalarized + pipelined, strided w ----------------
__global__ void k_gather(const int* __restrict__ ei, const int* __restrict__ offs,
                         const int* __restrict__ csr, const bf16* __restrict__ w,
                         int wstride, const float* __restrict__ invdeg,
                         const bf16* __restrict__ X, bf16* __restrict__ Z) {
    int wid = (blockIdx.x * 256 + threadIdx.x) >> 6;
    int lane = threadIdx.x & 63;
    if (wid >= NP) return;
    float acc[KG];
#pragma unroll
    for (int k = 0; k < KG; k++) acc[k] = 0.0f;
    int beg = rfl(offs[wid]);
    int end = rfl(offs[wid + 1]);
    int cnt = end - beg;

    int e0 = csr_at(csr, beg + 0);
    int e1 = csr_at(csr, beg + 1);
    int e2 = csr_at(csr, beg + 2);
    int s1 = rfl(ei[e1]);
    const unsigned* wp0 = (const unsigned*)(w + (size_t)e0 * wstride);
    unsigned c0 = wp0[0], c1 = wp0[1], c2 = wp0[2], c3 = wp0[3], c4 = wp0[4];
    const unsigned* wp1 = (const unsigned*)(w + (size_t)e1 * wstride);
    unsigned n0 = wp1[0], n1 = wp1[1], n2 = wp1[2], n3 = wp1[3], n4 = wp1[4];
    int s0 = rfl(ei[e0]);
    float xv = ldx_frag(X, s0, lane);

    for (int t = 0; t < cnt; ++t) {
        int e3 = csr_at(csr, beg + t + 3);
        int s2 = rfl(ei[e2]);
        const unsigned* wp2 = (const unsigned*)(w + (size_t)e2 * wstride);
        unsigned m0 = wp2[0], m1 = wp2[1], m2 = wp2[2], m3 = wp2[3], m4 = wp2[4];
        float xv1 = ldx_frag(X, s1, lane);
        acc[0] += blo(c0) * xv; acc[1] += bhi(c0) * xv;
        acc[2] += blo(c1) * xv; acc[3] += bhi(c1) * xv;
        acc[4] += blo(c2) * xv; acc[5] += bhi(c2) * xv;
        acc[6] += blo(c3) * xv; acc[7] += bhi(c3) * xv;
        acc[8] += blo(c4) * xv; acc[9] += bhi(c4) * xv;
        e2 = e3; s1 = s2; xv = xv1;
        c0 = n0; c1 = n1; c2 = n2; c3 = n3; c4 = n4;
        n0 = m0; n1 = m1; n2 = m2; n3 = m3; n4 = m4;
    }
    store_zf(Z, wid, lane, acc, invdeg[wid]);
}

// ---------------- LDS-free frag-layout GEMM, pipelined, MT m-frags/wave ----------
// Wave owns MT*16 rows; B loads amortized over MT m-frags (halves B L2 traffic
// at MT=2) and MT*NT MFMAs per iteration cover load latency.
// MODE 0: hf(frag) = relu(acc+bias) | MODE 1: ys(row-major) = acc+bias
// MODE 2: out = relu(acc+bias+addsrc), dtype per flag
template <int NT, int MODE>
__device__ __forceinline__ void gemm_body(
    int bid, const bf16* __restrict__ Zf, const bf16* __restrict__ Xf,
    const bf16* __restrict__ Bp, const void* __restrict__ bias, int f,
    const bf16* __restrict__ addsrc, bf16* __restrict__ outb,
    void* __restrict__ outp) {
    constexpr int Cout = NT * 16;
    constexpr int MT = 2;
    int lane = threadIdx.x & 63;
    int wave = threadIdx.x >> 6;
    int m = lane & 15, quad = lane >> 4;
    int row0 = bid * (64 * MT) + wave * (16 * MT);

    const bf16* bbase = Bp + (size_t)lane * 8;
    const bf16* arow[MT];
    const bf16* xrow[MT];
#pragma unroll
    for (int mt = 0; mt < MT; mt++) {
        arow[mt] = Zf + (size_t)(row0 + mt * 16 + m) * 32 + quad * 8;
        xrow[mt] = Xf + (size_t)(row0 + mt * 16 + m) * 32 + quad * 8;
    }

    float4v acc[MT][NT];
#pragma unroll
    for (int mt = 0; mt < MT; mt++)
#pragma unroll
        for (int n = 0; n < NT; n++) acc[mt][n] = (float4v){0.f, 0.f, 0.f, 0.f};

    // rolling A queue, depth 2 per m-frag (kc 0..19 from Zf, 20..21 from Xf)
    short8 apre[MT][2];
#pragma unroll
    for (int mt = 0; mt < MT; mt++)
#pragma unroll
        for (int i = 0; i < 2; i++)
            apre[mt][i] = *(const short8*)(arow[mt] + (size_t)i * NPAD * 32);
    // B double buffer
    short8 bcur[NT];
#pragma unroll
    for (int n = 0; n < NT; n++)
        bcur[n] = *(const short8*)(bbase + (size_t)(n * 22 + 0) * 512);

#pragma unroll
    for (int kc = 0; kc < 22; kc++) {
        short8 a[MT];
#pragma unroll
        for (int mt = 0; mt < MT; mt++) a[mt] = apre[mt][kc & 1];
        int kn = kc + 2;
        if (kn < 22) {
#pragma unroll
            for (int mt = 0; mt < MT; mt++)
                apre[mt][kc & 1] = (kn < 20)
                    ? *(const short8*)(arow[mt] + (size_t)kn * NPAD * 32)
                    : *(const short8*)(xrow[mt] + (size_t)(kn - 20) * NPAD * 32);
        }
        short8 bnxt[NT];
        if (kc + 1 < 22) {
#pragma unroll
            for (int n = 0; n < NT; n++)
                bnxt[n] = *(const short8*)(bbase + (size_t)(n * 22 + kc + 1) * 512);
        }
#pragma unroll
        for (int n = 0; n < NT; n++)
#pragma unroll
            for (int mt = 0; mt < MT; mt++)
                acc[mt][n] = __builtin_amdgcn_mfma_f32_16x16x32_bf16(a[mt], bcur[n],
                                                                     acc[mt][n], 0, 0, 0);
        if (kc + 1 < 22) {
#pragma unroll
            for (int n = 0; n < NT; n++) bcur[n] = bnxt[n];
        }
    }

    // epilogue: C/D layout col = lane&15, row = quad*4 + r
#pragma unroll
    for (int mt = 0; mt < MT; mt++) {
#pragma unroll
        for (int n = 0; n < NT; n++) {
            int gcol = n * 16 + m;
            float bv = ldf(bias, gcol, f);
#pragma unroll
            for (int r = 0; r < 4; r++) {
                int grow = row0 + mt * 16 + quad * 4 + r;
                if (grow >= N_NODES) continue;
                float v = acc[mt][n][r] + bv;
                if (MODE == 0) {
                    outb[((size_t)(gcol >> 5) * NPAD + grow) * 32 + (gcol & 31)] =
                        __float2bfloat16(fmaxf(v, 0.f));
                } else if (MODE == 1) {
                    outb[(size_t)grow * Cout + gcol] = __float2bfloat16(v);
                } else {
                    size_t oidx = (size_t)grow * Cout + gcol;
                    v = fmaxf(v + __bfloat162float(addsrc[oidx]), 0.f);
                    if (f) ((float*)outp)[oidx] = v;
                    else   ((bf16*)outp)[oidx] = __float2bfloat16(v);
                }
            }
        }
    }
}

// conv1 (NT=4 -> hf) and shortcut (NT=8 -> ys) merged: one dispatch
__global__ __launch_bounds__(256) void k_gemm_pair(
    const bf16* __restrict__ za, const bf16* __restrict__ zb,
    const bf16* __restrict__ Xf, const bf16* __restrict__ wt1p,
    const bf16* __restrict__ wtsp, const void* __restrict__ b1,
    const void* __restrict__ bs, const int* __restrict__ flag,
    bf16* __restrict__ hf, bf16* __restrict__ ys) {
    int f = flag[0];
    if (blockIdx.x < GRIDM)
        gemm_body<4, 0>(blockIdx.x, za, Xf, wt1p, b1, f, nullptr, hf, nullptr);
    else
        gemm_body<8, 1>(blockIdx.x - GRIDM, zb, Xf, wtsp, bs, f, nullptr, ys, nullptr);
}

template <int NT, int MODE>
__global__ __launch_bounds__(256) void k_gemm_one(
    const bf16* __restrict__ Zf, const bf16* __restrict__ Xf,
    const bf16* __restrict__ Bp, const void* __restrict__ bias,
    const int* __restrict__ flag, const bf16* __restrict__ addsrc,
    bf16* __restrict__ outb, void* __restrict__ outp) {
    gemm_body<NT, MODE>(blockIdx.x, Zf, Xf, Bp, bias, flag[0], addsrc, outb, outp);
}

extern "C" void kernel_launch(void* const* d_in, const int* in_sizes, int n_in,
                              void* d_out, int out_size, void* d_ws, size_t ws_size,
                              hipStream_t stream) {
    const void* x      = d_in[0];
    const int*  ei     = (const int*)d_in[1];
    const void* pseudo = d_in[2];
    const void* g1     = d_in[3];
    const void* mu1    = d_in[4];
    const void* sg1    = d_in[5];
    const void* root1  = d_in[6];
    const void* b1     = d_in[7];
    const void* g2     = d_in[8];
    const void* mu2    = d_in[9];
    const void* sg2    = d_in[10];
    const void* root2  = d_in[11];
    const void* b2     = d_in[12];
    const void* gs     = d_in[13];
    const void* mus    = d_in[14];
    const void* sgs    = d_in[15];
    const void* roots  = d_in[16];
    const void* bs     = d_in[17];

    char* ws = (char*)d_ws;
    size_t off = 0;
    auto alloc = [&](size_t bytes) -> char* {
        char* p = ws + off;
        off += (bytes + 255) & ~(size_t)255;
        return p;
    };
    const size_t ZSZ = (size_t)20 * NPAD * 32 * 2;   // 52.6 MB frag-layout z
    const size_t XFS = (size_t)2 * NPAD * 32 * 2;    // 5.26 MB frag-layout x/h

    int*   flag   = (int*)alloc(256);
    int*   deg    = (int*)alloc((size_t)NP * 4);
    int*   offs   = (int*)alloc((size_t)(NP + 1) * 4);
    int*   cur    = (int*)alloc((size_t)NP * 4);
    float* invdeg = (float*)alloc((size_t)NP * 4);
    int*   bsum   = (int*)alloc((size_t)NBLK * 4);
    int*   csr    = (int*)alloc((size_t)N_EDGES * 4);
    bf16*  Xf     = (bf16*)alloc(XFS);
    bf16*  hf     = (bf16*)alloc(XFS);
    bf16*  ys     = (bf16*)alloc((size_t)N_NODES * 128 * 2);
    bf16*  wt1p   = (bf16*)alloc((size_t)64 * 704 * 2);
    bf16*  wt2p   = (bf16*)alloc((size_t)128 * 704 * 2);
    bf16*  wtsp   = (bf16*)alloc((size_t)128 * 704 * 2);
    bf16*  wab    = (bf16*)alloc((size_t)N_EDGES * 20 * 2);   // {w1, wss}
    bf16*  w2b    = (bf16*)alloc((size_t)N_EDGES * 10 * 2);   // w2
    size_t common_end = off;

    bf16* za = (bf16*)alloc(ZSZ);
    bf16* zb = (bf16*)alloc(ZSZ);
    bool big = (off <= ws_size);

    hipMemsetAsync(deg, 0, (size_t)NP * 4, stream);
    k_detect_count<<<1 + (N_EDGES + 255) / 256, 256, 0, stream>>>(x, ei, flag, deg);
    k_prep_all<<<CVT_BLK + W3_BLK + PACK_BLK, 256, 0, stream>>>(
        x, pseudo, mu1, sg1, mu2, sg2, mus, sgs, g1, root1, g2, root2, gs, roots,
        flag, Xf, wab, w2b, wt1p, wt2p, wtsp);
    k_scan1<<<NBLK, SCAN_B, 0, stream>>>(deg, offs, bsum);
    k_scan3m<<<NBLK, 256, 0, stream>>>(offs, bsum, deg, cur, invdeg);
    k_fill<<<(N_EDGES + 255) / 256, 256, 0, stream>>>(ei, cur, csr);

    if (big) {
        k_gather2<<<NP / 4, 256, 0, stream>>>(ei, offs, csr, wab, invdeg, Xf, za, zb);
        k_gemm_pair<<<2 * GRIDM, 256, 0, stream>>>(za, zb, Xf, wt1p, wtsp, b1, bs,
                                                   flag, hf, ys);
        k_gather<<<NP / 4, 256, 0, stream>>>(ei, offs, csr, w2b, 10, invdeg, hf, za);
        k_gemm_one<8, 2><<<GRIDM, 256, 0, stream>>>(za, hf, wt2p, b2, flag, ys,
                                                    (bf16*)nullptr, d_out);
    } else {
        // fallback: one z buffer, sequential convs
        off = common_end;
        bf16* z = (bf16*)alloc(ZSZ);
        k_gather<<<NP / 4, 256, 0, stream>>>(ei, offs, csr, wab, 20, invdeg, Xf, z);
        k_gemm_one<4, 0><<<GRIDM, 256, 0, stream>>>(z, Xf, wt1p, b1, flag,
                                                    (const bf16*)nullptr, hf, nullptr);
        k_gather<<<NP / 4, 256, 0, stream>>>(ei, offs, csr, wab + 10, 20, invdeg, Xf, z);
        k_gemm_one<8, 1><<<GRIDM, 256, 0, stream>>>(z, Xf, wtsp, bs, flag,
                                                    (const bf16*)nullptr, ys, nullptr);
        k_gather<<<NP / 4, 256, 0, stream>>>(ei, offs, csr, w2b, 10, invdeg, hf, z);
        k_gemm_one<8, 2><<<GRIDM, 256, 0, stream>>>(z, hf, wt2p, b2, flag, ys,
                                                    (bf16*)nullptr, d_out);
    }
}

// Round 12
// 295.064 us; speedup vs baseline: 1.1140x; 1.1140x over previous
//
#include <hip/hip_runtime.h>
#include <hip/hip_bf16.h>

using bf16 = __hip_bfloat16;
typedef __attribute__((ext_vector_type(8))) short short8;
typedef __attribute__((ext_vector_type(4))) float float4v;

#define N_NODES 40962
#define N_EDGES 245760
#define NP      41024      // 641*64, padded node count
#define KG      10
#define SCAN_B  256
#define NBLK    ((NP + SCAN_B - 1) / SCAN_B)   // 161
#define GRID1   (NP / 64)                      // 641 gemm blocks (64 rows each)

// fused prep grid partition
#define CVT_V   (N_NODES * 64 / 8)             // 327696 vectors of 8
#define CVT_BLK ((CVT_V + 255) / 256)          // 1281
#define W3_BLK  (N_EDGES / 256)                // 960
#define PACK_N  (64 * 704 + 2 * 128 * 704)     // 225280
#define PACK_BLK (PACK_N / 256)                // 880

// k-dim ordering (shared by z stores, x/h frag layout, and B pack):
//   k in [0,512):   cin = k>>3,        kg = k&7      (k = cin*8+kg)
//   k in [512,640): cin = (k-512)>>1,  kg = 8+((k-512)&1)
//   k in [640,704): root row cin = k-640
// Frag layouts (no LDS GEMM; memory layout == MFMA fragment layout):
//   Zf[kc][node][32]  kc=0..19  : element t -> k = kc*32+t
//   Xf/hf[c][node][32] c=0..1   : element t -> cin = c*32+t (root part)
//   Bp[((n*22+kc)*64+lane)*8+j] : col = n*16+(lane&15), k = kc*32+(lane>>4)*8+j

// flag[0] == 1 -> float inputs/outputs are f32 ; 0 -> bf16
__device__ __forceinline__ float ldf(const void* p, size_t i, int isf32) {
    return isf32 ? ((const float*)p)[i] : __bfloat162float(((const bf16*)p)[i]);
}
__device__ __forceinline__ float blo(unsigned u) { return __uint_as_float(u << 16); }
__device__ __forceinline__ float bhi(unsigned u) { return __uint_as_float(u & 0xffff0000u); }
__device__ __forceinline__ unsigned pk2(float a, float b) {
    union { bf16 h[2]; unsigned u; } t;
    t.h[0] = __float2bfloat16(a);
    t.h[1] = __float2bfloat16(b);
    return t.u;
}
__device__ __forceinline__ int rfl(int v) { return __builtin_amdgcn_readfirstlane(v); }

// ---------------- fused dtype detector + degree count ----------------
__global__ void k_detect_count(const void* x, const int* __restrict__ ei,
                               int* __restrict__ flag, int* __restrict__ deg) {
    if (blockIdx.x == 0) {
        __shared__ int huge_c, zero_even;
        if (threadIdx.x == 0) { huge_c = 0; zero_even = 0; }
        __syncthreads();
        const bf16* xb = (const bf16*)x;
        int lh = 0, lz = 0;
        for (int i = threadIdx.x; i < 8192; i += 256) {
            float v = __bfloat162float(xb[i]);
            if (!(fabsf(v) <= 1e4f)) lh++;
            if ((i & 1) == 0 && v == 0.0f) lz++;
        }
        atomicAdd(&huge_c, lh);
        atomicAdd(&zero_even, lz);
        __syncthreads();
        if (threadIdx.x == 0) flag[0] = (huge_c > 0 || zero_even > 3000) ? 1 : 0;
    } else {
        int e = (blockIdx.x - 1) * 256 + threadIdx.x;
        if (e < N_EDGES) atomicAdd(&deg[ei[N_EDGES + e]], 1);
    }
}

// ---------------- scan stage 1: block-local exclusive + block sums ----------------
__global__ void k_scan1(const int* __restrict__ deg, int* __restrict__ offs,
                        int* __restrict__ bsum) {
    __shared__ int buf[SCAN_B];
    int t = threadIdx.x, b = blockIdx.x;
    int i = b * SCAN_B + t;
    int v = (i < NP) ? deg[i] : 0;
    buf[t] = v;
    __syncthreads();
    for (int off = 1; off < SCAN_B; off <<= 1) {
        int a = (t >= off) ? buf[t - off] : 0;
        __syncthreads();
        buf[t] += a;
        __syncthreads();
    }
    if (i < NP) offs[i] = buf[t] - v;
    if (t == SCAN_B - 1) bsum[b] = buf[t];
}

// ---------------- scan stage 2 (merged): each block re-scans bsum locally ----------------
__global__ void k_scan3m(int* __restrict__ offs, const int* __restrict__ bsum,
                         const int* __restrict__ deg, int* __restrict__ cur,
                         float* __restrict__ invdeg) {
    __shared__ int buf[256];
    int t = threadIdx.x, b = blockIdx.x;
    int v = (t < NBLK) ? bsum[t] : 0;
    buf[t] = v;
    __syncthreads();
    for (int off = 1; off < 256; off <<= 1) {
        int a = (t >= off) ? buf[t - off] : 0;
        __syncthreads();
        buf[t] += a;
        __syncthreads();
    }
    int bofs = (b > 0) ? buf[b - 1] : 0;
    int total = buf[NBLK - 1];
    int i = b * 256 + t;
    if (i < NP) {
        int o = offs[i] + bofs;
        offs[i] = o;
        cur[i] = o;
        int d = deg[i];
        invdeg[i] = 1.0f / (float)(d > 1 ? d : 1);
    }
    if (i == 0) offs[NP] = total;
}

// ---------------- CSR fill ----------------
__global__ void k_fill(const int* __restrict__ ei, int* __restrict__ cur,
                       int* __restrict__ csr) {
    int e = blockIdx.x * 256 + threadIdx.x;
    if (e < N_EDGES) {
        int pos = atomicAdd(&cur[ei[N_EDGES + e]], 1);
        csr[pos] = e;
    }
}

// ---------------- gaussian weights helper ----------------
__device__ __forceinline__ void gw_one(float p0, float p1, const void* mu,
                                       const void* sg, int f, float* out) {
#pragma unroll
    for (int k = 0; k < KG; k++) {
        float m0 = ldf(mu, 2 * k + 0, f), m1 = ldf(mu, 2 * k + 1, f);
        float s0 = ldf(sg, 2 * k + 0, f), s1 = ldf(sg, 2 * k + 1, f);
        float d0 = p0 - m0, d1 = p1 - m1;
        float t = -0.5f * (d0 * d0 / (1e-15f + s0 * s0) + d1 * d1 / (1e-15f + s1 * s1));
        out[k] = __expf(t);
    }
}

// ---------------- B pack in fragment order ----------------
__device__ __forceinline__ void pack_frag(const void* g, const void* root, int f,
                                          int idx, int Cout, bf16* Bp) {
    int j = idx & 7;
    int lane = (idx >> 3) & 63;
    int rem = idx >> 9;
    int kc = rem % 22;
    int n = rem / 22;
    int col = n * 16 + (lane & 15);
    int k = kc * 32 + (lane >> 4) * 8 + j;
    float v;
    if (k < 512) {
        int cin = k >> 3, kg = k & 7;
        v = ldf(g, (size_t)cin * (KG * Cout) + (size_t)kg * Cout + col, f);
    } else if (k < 640) {
        int jj = k - 512;
        int cin = jj >> 1, kg = 8 + (jj & 1);
        v = ldf(g, (size_t)cin * (KG * Cout) + (size_t)kg * Cout + col, f);
    } else {
        v = ldf(root, (size_t)(k - 640) * Cout + col, f);
    }
    Bp[idx] = __float2bfloat16(v);
}

// ---------------- fused prep: cvt x->Xf | w3 | pack3 ----------------
__global__ void k_prep_all(const void* __restrict__ x, const void* __restrict__ pseudo,
                           const void* mu1, const void* sg1, const void* mu2,
                           const void* sg2, const void* mus, const void* sgs,
                           const void* g1, const void* root1, const void* g2,
                           const void* root2, const void* gs, const void* roots,
                           const int* __restrict__ flag, bf16* __restrict__ Xf,
                           bf16* __restrict__ wab, bf16* __restrict__ w2b,
                           bf16* wt1p, bf16* wt2p, bf16* wtsp) {
    int b = blockIdx.x;
    int tid = threadIdx.x;
    int f = flag[0];
    if (b < CVT_BLK) {
        int i = b * 256 + tid;
        if (i < CVT_V) {
            int node = i >> 3, j = i & 7;   // covers x[node][j*8 .. j*8+8)
            uint4 u;
            if (f) {
                const float4* xf = (const float4*)x;
                float4 a = xf[2 * i], c = xf[2 * i + 1];
                union { bf16 t[8]; uint4 u; } tt;
                tt.t[0] = __float2bfloat16(a.x); tt.t[1] = __float2bfloat16(a.y);
                tt.t[2] = __float2bfloat16(a.z); tt.t[3] = __float2bfloat16(a.w);
                tt.t[4] = __float2bfloat16(c.x); tt.t[5] = __float2bfloat16(c.y);
                tt.t[6] = __float2bfloat16(c.z); tt.t[7] = __float2bfloat16(c.w);
                u = tt.u;
            } else {
                u = ((const uint4*)x)[i];
            }
            *(uint4*)(Xf + ((size_t)(j >> 2) * NP + node) * 32 + (j & 3) * 8) = u;
        }
    } else if (b < CVT_BLK + W3_BLK) {
        int e = (b - CVT_BLK) * 256 + tid;
        float p0 = ldf(pseudo, (size_t)e * 2 + 0, f);
        float p1 = ldf(pseudo, (size_t)e * 2 + 1, f);
        float o1[KG], o2[KG], os[KG];
        gw_one(p0, p1, mu1, sg1, f, o1);
        gw_one(p0, p1, mu2, sg2, f, o2);
        gw_one(p0, p1, mus, sgs, f, os);
        unsigned* d = (unsigned*)(wab + (size_t)e * 20);
        d[0] = pk2(o1[0], o1[1]); d[1] = pk2(o1[2], o1[3]);
        d[2] = pk2(o1[4], o1[5]); d[3] = pk2(o1[6], o1[7]);
        d[4] = pk2(o1[8], o1[9]);
        d[5] = pk2(os[0], os[1]); d[6] = pk2(os[2], os[3]);
        d[7] = pk2(os[4], os[5]); d[8] = pk2(os[6], os[7]);
        d[9] = pk2(os[8], os[9]);
        unsigned* d2 = (unsigned*)(w2b + (size_t)e * 10);
        d2[0] = pk2(o2[0], o2[1]); d2[1] = pk2(o2[2], o2[3]);
        d2[2] = pk2(o2[4], o2[5]); d2[3] = pk2(o2[6], o2[7]);
        d2[4] = pk2(o2[8], o2[9]);
    } else {
        int idx = (b - CVT_BLK - W3_BLK) * 256 + tid;
        if (idx < 64 * 704) {
            pack_frag(g1, root1, f, idx, 64, wt1p);
        } else if (idx < 64 * 704 + 128 * 704) {
            pack_frag(g2, root2, f, idx - 64 * 704, 128, wt2p);
        } else {
            pack_frag(gs, roots, f, idx - 64 * 704 - 128 * 704, 128, wtsp);
        }
    }
}

// ---------------- z store into frag layout Zf[kc][node][32] ----------------
__device__ __forceinline__ void store_zf(bf16* Zf, int wid, int lane, const float* a,
                                         float inv) {
    union { bf16 h[8]; uint4 u; } p;
#pragma unroll
    for (int k = 0; k < 8; k++) p.h[k] = __float2bfloat16(a[k] * inv);
    *(uint4*)(Zf + ((size_t)(lane >> 2) * NP + wid) * 32 + (lane & 3) * 8) = p.u;
    *(unsigned*)(Zf + ((size_t)(16 + (lane >> 4)) * NP + wid) * 32 + (lane & 15) * 2) =
        pk2(a[8] * inv, a[9] * inv);
}

// X frag-layout read: cin = lane -> chunk lane>>5, t = lane&31
__device__ __forceinline__ float ldx_frag(const bf16* X, int src, int lane) {
    return __bfloat162float(X[((size_t)(lane >> 5) * NP + src) * 32 + (lane & 31)]);
}

__device__ __forceinline__ int csr_at(const int* csr, int idx) {
    if (idx > N_EDGES - 1) idx = N_EDGES - 1;
    return rfl(csr[idx]);
}

// ---------------- dual gather, scalarized + software-pipelined ----------------
__global__ void k_gather2(const int* __restrict__ ei, const int* __restrict__ offs,
                          const int* __restrict__ csr, const bf16* __restrict__ wab,
                          const float* __restrict__ invdeg, const bf16* __restrict__ X,
                          bf16* __restrict__ Za, bf16* __restrict__ Zb) {
    int wid = (blockIdx.x * 256 + threadIdx.x) >> 6;
    int lane = threadIdx.x & 63;
    if (wid >= NP) return;
    float aa[KG], ab[KG];
#pragma unroll
    for (int k = 0; k < KG; k++) { aa[k] = 0.0f; ab[k] = 0.0f; }
    int beg = rfl(offs[wid]);
    int end = rfl(offs[wid + 1]);
    int cnt = end - beg;

    int e0 = csr_at(csr, beg + 0);
    int e1 = csr_at(csr, beg + 1);
    int e2 = csr_at(csr, beg + 2);
    int s1 = rfl(ei[e1]);
    const unsigned* wp0 = (const unsigned*)(wab + (size_t)e0 * 20);
    unsigned c0 = wp0[0], c1 = wp0[1], c2 = wp0[2], c3 = wp0[3], c4 = wp0[4];
    unsigned c5 = wp0[5], c6 = wp0[6], c7 = wp0[7], c8 = wp0[8], c9 = wp0[9];
    const unsigned* wp1 = (const unsigned*)(wab + (size_t)e1 * 20);
    unsigned n0 = wp1[0], n1 = wp1[1], n2 = wp1[2], n3 = wp1[3], n4 = wp1[4];
    unsigned n5 = wp1[5], n6 = wp1[6], n7 = wp1[7], n8 = wp1[8], n9 = wp1[9];
    int s0 = rfl(ei[e0]);
    float xv = ldx_frag(X, s0, lane);

    for (int t = 0; t < cnt; ++t) {
        int e3 = csr_at(csr, beg + t + 3);
        int s2 = rfl(ei[e2]);
        const unsigned* wp2 = (const unsigned*)(wab + (size_t)e2 * 20);
        unsigned m0 = wp2[0], m1 = wp2[1], m2 = wp2[2], m3 = wp2[3], m4 = wp2[4];
        unsigned m5 = wp2[5], m6 = wp2[6], m7 = wp2[7], m8 = wp2[8], m9 = wp2[9];
        float xv1 = ldx_frag(X, s1, lane);
        aa[0] += blo(c0) * xv; aa[1] += bhi(c0) * xv;
        aa[2] += blo(c1) * xv; aa[3] += bhi(c1) * xv;
        aa[4] += blo(c2) * xv; aa[5] += bhi(c2) * xv;
        aa[6] += blo(c3) * xv; aa[7] += bhi(c3) * xv;
        aa[8] += blo(c4) * xv; aa[9] += bhi(c4) * xv;
        ab[0] += blo(c5) * xv; ab[1] += bhi(c5) * xv;
        ab[2] += blo(c6) * xv; ab[3] += bhi(c6) * xv;
        ab[4] += blo(c7) * xv; ab[5] += bhi(c7) * xv;
        ab[6] += blo(c8) * xv; ab[7] += bhi(c8) * xv;
        ab[8] += blo(c9) * xv; ab[9] += bhi(c9) * xv;
        e2 = e3; s1 = s2; xv = xv1;
        c0 = n0; c1 = n1; c2 = n2; c3 = n3; c4 = n4;
        c5 = n5; c6 = n6; c7 = n7; c8 = n8; c9 = n9;
        n0 = m0; n1 = m1; n2 = m2; n3 = m3; n4 = m4;
        n5 = m5; n6 = m6; n7 = m7; n8 = m8; n9 = m9;
    }
    float inv = invdeg[wid];
    store_zf(Za, wid, lane, aa, inv);
    store_zf(Zb, wid, lane, ab, inv);
}

// ---------------- single gather, scalarized + pipelined, strided w ----------------
__global__ void k_gather(const int* __restrict__ ei, const int* __restrict__ offs,
                         const int* __restrict__ csr, const bf16* __restrict__ w,
                         int wstride, const float* __restrict__ invdeg,
                         const bf16* __restrict__ X, bf16* __restrict__ Z) {
    int wid = (blockIdx.x * 256 + threadIdx.x) >> 6;
    int lane = threadIdx.x & 63;
    if (wid >= NP) return;
    float acc[KG];
#pragma unroll
    for (int k = 0; k < KG; k++) acc[k] = 0.0f;
    int beg = rfl(offs[wid]);
    int end = rfl(offs[wid + 1]);
    int cnt = end - beg;

    int e0 = csr_at(csr, beg + 0);
    int e1 = csr_at(csr, beg + 1);
    int e2 = csr_at(csr, beg + 2);
    int s1 = rfl(ei[e1]);
    const unsigned* wp0 = (const unsigned*)(w + (size_t)e0 * wstride);
    unsigned c0 = wp0[0], c1 = wp0[1], c2 = wp0[2], c3 = wp0[3], c4 = wp0[4];
    const unsigned* wp1 = (const unsigned*)(w + (size_t)e1 * wstride);
    unsigned n0 = wp1[0], n1 = wp1[1], n2 = wp1[2], n3 = wp1[3], n4 = wp1[4];
    int s0 = rfl(ei[e0]);
    float xv = ldx_frag(X, s0, lane);

    for (int t = 0; t < cnt; ++t) {
        int e3 = csr_at(csr, beg + t + 3);
        int s2 = rfl(ei[e2]);
        const unsigned* wp2 = (const unsigned*)(w + (size_t)e2 * wstride);
        unsigned m0 = wp2[0], m1 = wp2[1], m2 = wp2[2], m3 = wp2[3], m4 = wp2[4];
        float xv1 = ldx_frag(X, s1, lane);
        acc[0] += blo(c0) * xv; acc[1] += bhi(c0) * xv;
        acc[2] += blo(c1) * xv; acc[3] += bhi(c1) * xv;
        acc[4] += blo(c2) * xv; acc[5] += bhi(c2) * xv;
        acc[6] += blo(c3) * xv; acc[7] += bhi(c3) * xv;
        acc[8] += blo(c4) * xv; acc[9] += bhi(c4) * xv;
        e2 = e3; s1 = s2; xv = xv1;
        c0 = n0; c1 = n1; c2 = n2; c3 = n3; c4 = n4;
        n0 = m0; n1 = m1; n2 = m2; n3 = m3; n4 = m4;
    }
    store_zf(Z, wid, lane, acc, invdeg[wid]);
}

// ---------------- LDS-free frag-layout GEMM, pipelined (A-depth AD, B-depth 2) ----
// R10 structure (wave = 16 rows, MT=1, GRID1 blocks); B prefetch deepened to 2
// to cover the ~200cyc L2 B-load latency across two kc iterations.
// MODE 0: hf(frag) = relu(acc+bias) | MODE 1: ys(row-major) = acc+bias
// MODE 2: out = relu(acc+bias+addsrc), dtype per flag
template <int NT, int MODE>
__device__ __forceinline__ void gemm_body(
    int bid, const bf16* __restrict__ Zf, const bf16* __restrict__ Xf,
    const bf16* __restrict__ Bp, const void* __restrict__ bias, int f,
    const bf16* __restrict__ addsrc, bf16* __restrict__ outb,
    void* __restrict__ outp) {
    constexpr int Cout = NT * 16;
    constexpr int AD = (NT == 8) ? 2 : 4;   // A-prefetch depth (VGPR budget)
    int lane = threadIdx.x & 63;
    int wave = threadIdx.x >> 6;
    int m = lane & 15, quad = lane >> 4;
    int row0 = bid * 64 + wave * 16;

    const bf16* bbase = Bp + (size_t)lane * 8;
    const bf16* arow = Zf + ((size_t)(row0 + m)) * 32 + quad * 8;
    const bf16* xrow = Xf + ((size_t)(row0 + m)) * 32 + quad * 8;

    float4v acc[NT];
#pragma unroll
    for (int n = 0; n < NT; n++) acc[n] = (float4v){0.f, 0.f, 0.f, 0.f};

    // rolling A queue, depth AD (kc 0..19 from Zf, 20..21 from Xf)
    short8 apre[AD];
#pragma unroll
    for (int i = 0; i < AD; i++)
        apre[i] = *(const short8*)(arow + (size_t)i * NP * 32);
    // B prefetch queue, depth 2
    short8 bpre[2][NT];
#pragma unroll
    for (int n = 0; n < NT; n++) {
        bpre[0][n] = *(const short8*)(bbase + (size_t)(n * 22 + 0) * 512);
        bpre[1][n] = *(const short8*)(bbase + (size_t)(n * 22 + 1) * 512);
    }

#pragma unroll
    for (int kc = 0; kc < 22; kc++) {
        short8 a = apre[kc % AD];
        int kn = kc + AD;
        if (kn < 22) {
            apre[kc % AD] = (kn < 20)
                ? *(const short8*)(arow + (size_t)kn * NP * 32)
                : *(const short8*)(xrow + (size_t)(kn - 20) * NP * 32);
        }
        short8 bcur[NT];
#pragma unroll
        for (int n = 0; n < NT; n++) bcur[n] = bpre[kc & 1][n];
        if (kc + 2 < 22) {
#pragma unroll
            for (int n = 0; n < NT; n++)
                bpre[kc & 1][n] =
                    *(const short8*)(bbase + (size_t)(n * 22 + kc + 2) * 512);
        }
#pragma unroll
        for (int n = 0; n < NT; n++)
            acc[n] = __builtin_amdgcn_mfma_f32_16x16x32_bf16(a, bcur[n], acc[n], 0, 0, 0);
    }

    // epilogue: C/D layout col = lane&15, row = quad*4 + r
#pragma unroll
    for (int n = 0; n < NT; n++) {
        int gcol = n * 16 + m;
        float bv = ldf(bias, gcol, f);
#pragma unroll
        for (int r = 0; r < 4; r++) {
            int grow = row0 + quad * 4 + r;
            if (grow >= N_NODES) continue;
            float v = acc[n][r] + bv;
            if (MODE == 0) {
                outb[((size_t)(gcol >> 5) * NP + grow) * 32 + (gcol & 31)] =
                    __float2bfloat16(fmaxf(v, 0.f));
            } else if (MODE == 1) {
                outb[(size_t)grow * Cout + gcol] = __float2bfloat16(v);
            } else {
                size_t oidx = (size_t)grow * Cout + gcol;
                v = fmaxf(v + __bfloat162float(addsrc[oidx]), 0.f);
                if (f) ((float*)outp)[oidx] = v;
                else   ((bf16*)outp)[oidx] = __float2bfloat16(v);
            }
        }
    }
}

// conv1 (NT=4 -> hf) and shortcut (NT=8 -> ys) merged: one dispatch
__global__ __launch_bounds__(256) void k_gemm_pair(
    const bf16* __restrict__ za, const bf16* __restrict__ zb,
    const bf16* __restrict__ Xf, const bf16* __restrict__ wt1p,
    const bf16* __restrict__ wtsp, const void* __restrict__ b1,
    const void* __restrict__ bs, const int* __restrict__ flag,
    bf16* __restrict__ hf, bf16* __restrict__ ys) {
    int f = flag[0];
    if (blockIdx.x < GRID1)
        gemm_body<4, 0>(blockIdx.x, za, Xf, wt1p, b1, f, nullptr, hf, nullptr);
    else
        gemm_body<8, 1>(blockIdx.x - GRID1, zb, Xf, wtsp, bs, f, nullptr, ys, nullptr);
}

template <int NT, int MODE>
__global__ __launch_bounds__(256) void k_gemm_one(
    const bf16* __restrict__ Zf, const bf16* __restrict__ Xf,
    const bf16* __restrict__ Bp, const void* __restrict__ bias,
    const int* __restrict__ flag, const bf16* __restrict__ addsrc,
    bf16* __restrict__ outb, void* __restrict__ outp) {
    gemm_body<NT, MODE>(blockIdx.x, Zf, Xf, Bp, bias, flag[0], addsrc, outb, outp);
}

extern "C" void kernel_launch(void* const* d_in, const int* in_sizes, int n_in,
                              void* d_out, int out_size, void* d_ws, size_t ws_size,
                              hipStream_t stream) {
    const void* x      = d_in[0];
    const int*  ei     = (const int*)d_in[1];
    const void* pseudo = d_in[2];
    const void* g1     = d_in[3];
    const void* mu1    = d_in[4];
    const void* sg1    = d_in[5];
    const void* root1  = d_in[6];
    const void* b1     = d_in[7];
    const void* g2     = d_in[8];
    const void* mu2    = d_in[9];
    const void* sg2    = d_in[10];
    const void* root2  = d_in[11];
    const void* b2     = d_in[12];
    const void* gs     = d_in[13];
    const void* mus    = d_in[14];
    const void* sgs    = d_in[15];
    const void* roots  = d_in[16];
    const void* bs     = d_in[17];

    char* ws = (char*)d_ws;
    size_t off = 0;
    auto alloc = [&](size_t bytes) -> char* {
        char* p = ws + off;
        off += (bytes + 255) & ~(size_t)255;
        return p;
    };
    const size_t ZSZ = (size_t)20 * NP * 32 * 2;     // 52.5 MB frag-layout z
    const size_t XFS = (size_t)2 * NP * 32 * 2;      // 5.25 MB frag-layout x/h

    int*   flag   = (int*)alloc(256);
    int*   deg    = (int*)alloc((size_t)NP * 4);
    int*   offs   = (int*)alloc((size_t)(NP + 1) * 4);
    int*   cur    = (int*)alloc((size_t)NP * 4);
    float* invdeg = (float*)alloc((size_t)NP * 4);
    int*   bsum   = (int*)alloc((size_t)NBLK * 4);
    int*   csr    = (int*)alloc((size_t)N_EDGES * 4);
    bf16*  Xf     = (bf16*)alloc(XFS);
    bf16*  hf     = (bf16*)alloc(XFS);
    bf16*  ys     = (bf16*)alloc((size_t)N_NODES * 128 * 2);
    bf16*  wt1p   = (bf16*)alloc((size_t)64 * 704 * 2);
    bf16*  wt2p   = (bf16*)alloc((size_t)128 * 704 * 2);
    bf16*  wtsp   = (bf16*)alloc((size_t)128 * 704 * 2);
    bf16*  wab    = (bf16*)alloc((size_t)N_EDGES * 20 * 2);   // {w1, wss}
    bf16*  w2b    = (bf16*)alloc((size_t)N_EDGES * 10 * 2);   // w2
    size_t common_end = off;

    bf16* za = (bf16*)alloc(ZSZ);
    bf16* zb = (bf16*)alloc(ZSZ);
    bool big = (off <= ws_size);

    hipMemsetAsync(deg, 0, (size_t)NP * 4, stream);
    k_detect_count<<<1 + (N_EDGES + 255) / 256, 256, 0, stream>>>(x, ei, flag, deg);
    k_prep_all<<<CVT_BLK + W3_BLK + PACK_BLK, 256, 0, stream>>>(
        x, pseudo, mu1, sg1, mu2, sg2, mus, sgs, g1, root1, g2, root2, gs, roots,
        flag, Xf, wab, w2b, wt1p, wt2p, wtsp);
    k_scan1<<<NBLK, SCAN_B, 0, stream>>>(deg, offs, bsum);
    k_scan3m<<<NBLK, 256, 0, stream>>>(offs, bsum, deg, cur, invdeg);
    k_fill<<<(N_EDGES + 255) / 256, 256, 0, stream>>>(ei, cur, csr);

    if (big) {
        k_gather2<<<NP / 4, 256, 0, stream>>>(ei, offs, csr, wab, invdeg, Xf, za, zb);
        k_gemm_pair<<<2 * GRID1, 256, 0, stream>>>(za, zb, Xf, wt1p, wtsp, b1, bs,
                                                   flag, hf, ys);
        k_gather<<<NP / 4, 256, 0, stream>>>(ei, offs, csr, w2b, 10, invdeg, hf, za);
        k_gemm_one<8, 2><<<GRID1, 256, 0, stream>>>(za, hf, wt2p, b2, flag, ys,
                                                    (bf16*)nullptr, d_out);
    } else {
        // fallback: one z buffer, sequential convs
        off = common_end;
        bf16* z = (bf16*)alloc(ZSZ);
        k_gather<<<NP / 4, 256, 0, stream>>>(ei, offs, csr, wab, 20, invdeg, Xf, z);
        k_gemm_one<4, 0><<<GRID1, 256, 0, stream>>>(z, Xf, wt1p, b1, flag,
                                                    (const bf16*)nullptr, hf, nullptr);
        k_gather<<<NP / 4, 256, 0, stream>>>(ei, offs, csr, wab + 10, 20, invdeg, Xf, z);
        k_gemm_one<8, 1><<<GRID1, 256, 0, stream>>>(z, Xf, wtsp, bs, flag,
                                                    (const bf16*)nullptr, ys, nullptr);
        k_gather<<<NP / 4, 256, 0, stream>>>(ei, offs, csr, w2b, 10, invdeg, hf, z);
        k_gemm_one<8, 2><<<GRID1, 256, 0, stream>>>(z, hf, wt2p, b2, flag, ys,
                                                    (bf16*)nullptr, d_out);
    }
}